// Round 1
// baseline (775.012 us; speedup 1.0000x reference)
//
#include <hip/hip_runtime.h>

// Problem: x [16, 512, 512, 32] f32 -> out [16, 512, 512, 1] f32
// out[b,h,w] = max over shifts S = {(0,0),(0,1),(1,0),(1,1),(0,2),(2,0),(2,2)}
//              of M[b, h-di, w-dj],  M = channel-max of x, OOB -> 0 (zero pad).
// Memory-bound: 537 MB read (+9.6% halo) + 16.8 MB write -> ~95 us floor @6.3 TB/s.
//
// v2 changes vs previous session's kernel:
//  - Phase-1 loads are quad-cooperative: 4 lanes per pixel, each lane loads
//    float4 slots jj and jj+4. Every global_load_dwordx4 is 16 full 64B
//    sectors (perfect TA coalescing) vs 64 fragmented sectors before.
//  - Tile 32x64 -> 2048 blocks -> 8 blocks/CU x 4 waves = 32 waves/CU (was 16),
//    and barrier bubbles are covered by 8 resident blocks (was 4).
//  - LDS row stride 67: phase-2 row reads drop to 2-way bank aliasing (free).
//  - Phase-2 computes 4 outputs/thread with row-register reuse, float4 stores.

#define HH 512
#define WW 512
#define CC 32
#define TH 32               // output tile rows
#define TW 64               // output tile cols
#define RH (TH + 2)         // 34: +2 backward halo rows (top side only)
#define RW (TW + 2)         // 66: +2 backward halo cols (left side only)
#define NPX (RH * RW)       // 2244 region pixels
#define LSTR 67             // LDS row stride; 67r mod 4 distinct per r -> 2-way max

__global__ __launch_bounds__(256, 8) void maxassign2d_kernel(
    const float* __restrict__ x, float* __restrict__ out) {
  __shared__ float m[RH * LSTR];   // 9112 B

  const int b   = blockIdx.z;
  const int h0  = blockIdx.y * TH;
  const int w0  = blockIdx.x * TW;
  const int tid = threadIdx.x;

  const int jj = tid & 3;   // float4 slot: loads slot jj and jj+4 of its pixel
  const int q  = tid >> 2;  // quad id 0..63: one pixel per quad per step

  // ---- Phase 1: channel-max of x into LDS for the 34x66 region ----
  // One pixel = 32 f32 = 128 B = 8 float4, covered by 4 lanes x 2 float4.
  // Unroll 2 pixels/thread/iter => 4 dwordx4 in flight per lane.
  for (unsigned p0 = q; p0 < NPX; p0 += 128) {
    const unsigned p1 = p0 + 64;

    const unsigned rr0 = p0 / RW;
    const unsigned cc0 = p0 - rr0 * RW;
    const int h_0 = h0 + (int)rr0 - 2;       // only low side can go OOB
    const int w_0 = w0 + (int)cc0 - 2;
    const bool g0 = (h_0 >= 0) && (w_0 >= 0);
    const float4* px0 =
        (const float4*)(x + (((long long)b * HH + h_0) * WW + w_0) * CC);

    const unsigned rr1 = p1 / RW;
    const unsigned cc1 = p1 - rr1 * RW;
    const int h_1 = h0 + (int)rr1 - 2;
    const int w_1 = w0 + (int)cc1 - 2;
    const bool g1 = (p1 < NPX) && (h_1 >= 0) && (w_1 >= 0);
    const float4* px1 =
        (const float4*)(x + (((long long)b * HH + h_1) * WW + w_1) * CC);

    const float4 z = make_float4(0.f, 0.f, 0.f, 0.f);
    float4 a0 = g0 ? px0[jj]     : z;   // pad value 0 joins the max at borders
    float4 b0 = g0 ? px0[jj + 4] : z;
    float4 a1 = g1 ? px1[jj]     : z;
    float4 b1 = g1 ? px1[jj + 4] : z;

    float v0 = fmaxf(fmaxf(fmaxf(a0.x, a0.y), fmaxf(a0.z, a0.w)),
                     fmaxf(fmaxf(b0.x, b0.y), fmaxf(b0.z, b0.w)));
    float v1 = fmaxf(fmaxf(fmaxf(a1.x, a1.y), fmaxf(a1.z, a1.w)),
                     fmaxf(fmaxf(b1.x, b1.y), fmaxf(b1.z, b1.w)));

    // intra-quad max (xor 1, 2 stay inside the 4-lane group)
    v0 = fmaxf(v0, __shfl_xor(v0, 1));
    v0 = fmaxf(v0, __shfl_xor(v0, 2));
    v1 = fmaxf(v1, __shfl_xor(v1, 1));
    v1 = fmaxf(v1, __shfl_xor(v1, 2));

    if (jj == 0) {
      m[rr0 * LSTR + cc0] = v0;                 // consecutive cc -> no conflict
      if (p1 < NPX) m[rr1 * LSTR + cc1] = v1;
    }
  }
  __syncthreads();

  // ---- Phase 2: 7-way backward-shift max over the LDS tile ----
  // Output (r,c) = max over region offsets {(0,0),(0,2),(1,1),(1,2),(2,0),(2,1),(2,2)}
  // relative to region coord (r,c) (output pixel itself sits at (r+2,c+2)).
  // 4 outputs/thread with shared row registers, float4 store.
  for (int s = tid; s < TH * TW / 4; s += 256) {  // 512 slots, 2 iters
    const int r = s >> 4;            // 0..31
    const int c = (s & 15) << 2;     // 0,4,...,60
    const float* base = &m[r * LSTR + c];
    float r0[6], r1[6], r2[6];
#pragma unroll
    for (int k = 0; k < 6; ++k) {
      r0[k] = base[k];
      r1[k] = base[LSTR + k];        // r1[0] dead -> DCE'd
      r2[k] = base[2 * LSTR + k];
    }
    float4 v;
    float* vp = &v.x;
#pragma unroll
    for (int k = 0; k < 4; ++k) {
      const float t0 = fmaxf(r0[k], r0[k + 2]);
      const float t1 = fmaxf(r1[k + 1], r1[k + 2]);
      const float t2 = fmaxf(fmaxf(r2[k], r2[k + 1]), r2[k + 2]);
      vp[k] = fmaxf(fmaxf(t0, t1), t2);
    }
    *(float4*)(out + ((long long)b * HH + h0 + r) * WW + w0 + c) = v;
  }
}

extern "C" void kernel_launch(void* const* d_in, const int* in_sizes, int n_in,
                              void* d_out, int out_size, void* d_ws, size_t ws_size,
                              hipStream_t stream) {
  const float* x = (const float*)d_in[0];
  float* out = (float*)d_out;
  const int B = in_sizes[0] / (HH * WW * CC);  // = 16
  dim3 grid(WW / TW, HH / TH, B);              // (8, 16, 16) = 2048 blocks
  maxassign2d_kernel<<<grid, 256, 0, stream>>>(x, out);
}

// Round 3
// 678.746 us; speedup vs baseline: 1.1418x; 1.1418x over previous
//
#include <hip/hip_runtime.h>

// Problem: x [16, 512, 512, 32] f32 -> out [16, 512, 512, 1] f32
// out[b,h,w] = max over shifts S = {(0,0),(0,1),(1,0),(1,1),(0,2),(2,0),(2,2)}
//              of M[b, h-di, w-dj],  M = channel-max of x, OOB -> 0 (zero pad).
// Memory-bound: 537 MB read + 16.8 MB write -> ~88 us floor at 6.3 TB/s.
//
// CONTROL EXPERIMENT (round 3 resubmit; round-2 run died in the broker,
// "container failed twice" — no data). Exact revert to the twice-measured
// 676/678 us kernel. Round-1's v2 (quad-cooperative loads + 32x64 tile +
// shfl reduce) measured 775 us (+97) with no identifiable mechanism;
// re-establish the baseline before attributing. If this reproduces ~678,
// v2's structure is abandoned and changes get re-introduced one at a time.
// If it lands ~775, the harness floor moved and v1 is roofline-within-noise.

#define HH 512
#define WW 512
#define CC 32
#define TILE 64
#define REG (TILE + 2)   // 66: backward halo of 2 in h and w
#define LSTR REG         // LDS row stride (66); phase-2 lanes read consecutive
                         // addresses within a row -> conflict-free, no pad needed

__global__ __launch_bounds__(256) void maxassign2d_kernel(
    const float* __restrict__ x, float* __restrict__ out) {
  __shared__ float m[REG * LSTR];

  const int b  = blockIdx.z;
  const int h0 = blockIdx.y * TILE;
  const int w0 = blockIdx.x * TILE;
  const int tid = threadIdx.x;

  // ---- Phase 1: channel-max of x into LDS for the 66x66 region ----
  // Each region pixel = 32 contiguous f32 = 128 B = one cache line,
  // read as 8x float4 by one thread.
  for (int p = tid; p < REG * REG; p += 256) {
    const int rr = p / REG;
    const int cc = p - rr * REG;
    const int h = h0 + rr - 2;   // max: 448+65-2 = 511 < 512, only low side can OOB
    const int w = w0 + cc - 2;
    float v = 0.0f;              // pad value: zero joins the max at borders
    if (h >= 0 && w >= 0) {
      const float4* px =
          (const float4*)(x + (((size_t)b * HH + h) * WW + w) * CC);
      float4 a0 = px[0], a1 = px[1], a2 = px[2], a3 = px[3];
      float4 a4 = px[4], a5 = px[5], a6 = px[6], a7 = px[7];
      float m0 = fmaxf(fmaxf(a0.x, a0.y), fmaxf(a0.z, a0.w));
      float m1 = fmaxf(fmaxf(a1.x, a1.y), fmaxf(a1.z, a1.w));
      float m2 = fmaxf(fmaxf(a2.x, a2.y), fmaxf(a2.z, a2.w));
      float m3 = fmaxf(fmaxf(a3.x, a3.y), fmaxf(a3.z, a3.w));
      float m4 = fmaxf(fmaxf(a4.x, a4.y), fmaxf(a4.z, a4.w));
      float m5 = fmaxf(fmaxf(a5.x, a5.y), fmaxf(a5.z, a5.w));
      float m6 = fmaxf(fmaxf(a6.x, a6.y), fmaxf(a6.z, a6.w));
      float m7 = fmaxf(fmaxf(a7.x, a7.y), fmaxf(a7.z, a7.w));
      v = fmaxf(fmaxf(fmaxf(m0, m1), fmaxf(m2, m3)),
                fmaxf(fmaxf(m4, m5), fmaxf(m6, m7)));
    }
    m[rr * LSTR + cc] = v;
  }
  __syncthreads();

  // ---- Phase 2: 7-way backward-shift max over the LDS tile ----
  // Output (r,c) sits at region coord (r+2, c+2); shift (di,dj) reads
  // region (r+2-di, c+2-dj).
  for (int p = tid; p < TILE * TILE; p += 256) {
    const int r = p >> 6;
    const int c = p & (TILE - 1);
    const float* base = &m[r * LSTR + c];
    float v = base[2 * LSTR + 2];              // (0,0)
    v = fmaxf(v, base[2 * LSTR + 1]);          // (0,1)
    v = fmaxf(v, base[1 * LSTR + 2]);          // (1,0)
    v = fmaxf(v, base[1 * LSTR + 1]);          // (1,1)
    v = fmaxf(v, base[2 * LSTR + 0]);          // (0,2)
    v = fmaxf(v, base[0 * LSTR + 2]);          // (2,0)
    v = fmaxf(v, base[0 * LSTR + 0]);          // (2,2)
    out[((size_t)b * HH + (h0 + r)) * WW + (w0 + c)] = v;
  }
}

extern "C" void kernel_launch(void* const* d_in, const int* in_sizes, int n_in,
                              void* d_out, int out_size, void* d_ws, size_t ws_size,
                              hipStream_t stream) {
  const float* x = (const float*)d_in[0];
  float* out = (float*)d_out;
  const int B = in_sizes[0] / (HH * WW * CC);  // = 16
  dim3 grid(WW / TILE, HH / TILE, B);          // (8, 8, 16)
  maxassign2d_kernel<<<grid, 256, 0, stream>>>(x, out);
}